// Round 16
// baseline (685.188 us; speedup 1.0000x reference)
//
#include <hip/hip_runtime.h>

typedef __bf16 bf16x8 __attribute__((ext_vector_type(8)));
typedef float f32x4 __attribute__((ext_vector_type(4)));
typedef float f32x16 __attribute__((ext_vector_type(16)));

#define B_ 2
#define T_ 2048
#define D_ 1024
#define H_ 16
#define NLOG4 -9.2103403719761836f  // -ln(10000)

__device__ __forceinline__ ushort f2bf(float f) {
  union { float f; unsigned u; } v; v.f = f;
  unsigned u = v.u;
  return (ushort)((u + 0x7FFFu + ((u >> 16) & 1u)) >> 16);
}

// async global->LDS, 16B per lane; LDS dest is wave-uniform base + lane*16
__device__ __forceinline__ void g2l16(const void* g, void* l) {
  __builtin_amdgcn_global_load_lds(
      (const __attribute__((address_space(1))) unsigned int*)g,
      (__attribute__((address_space(3))) unsigned int*)l, 16, 0, 0);
}

// ---------------- cast x -> bf16 ----------------
__global__ __launch_bounds__(256) void cvt_kernel(const float* __restrict__ in,
                                                  ushort* __restrict__ out) {
  int i = (blockIdx.x * 256 + threadIdx.x) * 4;
  float4 v = *(const float4*)(in + i);
  ushort4 o;
  o.x = f2bf(v.x); o.y = f2bf(v.y); o.z = f2bf(v.z); o.w = f2bf(v.w);
  *(ushort4*)(out + i) = o;
}

// ---------------- transpose + cast: in[R][C] f32 -> out[C][R] bf16 ----------------
__global__ void transpose_cvt(const float* __restrict__ in, ushort* __restrict__ out,
                              int R, int C) {
  __shared__ float tile[32][33];
  int bx = blockIdx.x * 32, by = blockIdx.y * 32;
  int tx = threadIdx.x, ty = threadIdx.y;  // block (32,8)
  for (int i = 0; i < 32; i += 8)
    tile[ty + i][tx] = in[(size_t)(by + ty + i) * C + (bx + tx)];
  __syncthreads();
  for (int i = 0; i < 32; i += 8)
    out[(size_t)(bx + ty + i) * R + (by + tx)] = f2bf(tile[tx][ty + i]);
}

// ---------------- Kaug trig half (data-independent) ----------------
// Ka layout [B*T, H, 128]: trig at [row, h, 64+2mm / 64+2mm+1]
__global__ __launch_bounds__(512) void fill_ktrig(ushort* __restrict__ Ka) {
  int t = blockIdx.x;
  int tid = threadIdx.x;           // 512 = 16 h x 32 mm
  int h = tid >> 5, mm = tid & 31;
  float w = __expf(NLOG4 * (float)(h * 64 + 2 * mm) * (1.0f / 1024.0f));
  float si, co;
  __sincosf(w * (float)t, &si, &co);
  ushort2 pk;
  pk.x = f2bf(co); pk.y = f2bf(si);
  for (int b = 0; b < 2; ++b)
    *(ushort2*)(Ka + ((size_t)(b * T_ + t) * 2048 + h * 128 + 64 + 2 * mm)) = pk;
}

// ---------------- QKV GEMM, fused augment epilogue (full-line stores) ----------------
// A[4096,1024] bf16, BT[3072,1024] bf16.
// slice0 -> Qa [B*T,H,128] (incl trig pair transform, x1/8); slice1 -> Ka base half;
// slice2 -> Va [B*T,H,64].
__global__ __launch_bounds__(256) void gemm_qkv(
    const ushort* __restrict__ A, const ushort* __restrict__ BT,
    ushort* __restrict__ Qa, ushort* __restrict__ Ka, ushort* __restrict__ Va) {
  __shared__ alignas(16) ushort As[2][4096];
  __shared__ alignas(16) ushort Bs[2][4096];
  int tid = threadIdx.x;
  int wave = tid >> 6, lane = tid & 63;
  int l16 = lane & 15, lhi = lane >> 4;
  int m0 = blockIdx.y * 128, n0 = blockIdx.x * 128;
  int wr = (wave >> 1) * 64, wc = (wave & 1) * 64;
  int srow = lane >> 2, sch = lane & 3;
  const int K = 1024;

  f32x4 acc[4][4] = {};

  auto stage = [&](int kk, int buf) {
    for (int i = 0; i < 2; ++i) {
      int rg = i * 4 + wave;
      g2l16(A + (size_t)(m0 + rg * 16 + srow) * K + kk + sch * 8, &As[buf][rg * 512]);
      g2l16(BT + (size_t)(n0 + rg * 16 + srow) * K + kk + sch * 8, &Bs[buf][rg * 512]);
    }
  };

  stage(0, 0);
  int buf = 0;
  for (int kk = 0; kk < K; kk += 32) {
    __syncthreads();
    if (kk + 32 < K) stage(kk + 32, buf ^ 1);
    const ushort* Asb = As[buf];
    const ushort* Bsb = Bs[buf];
    bf16x8 af[4], bfr[4];
    for (int f = 0; f < 4; ++f)
      af[f] = *(const bf16x8*)(Asb + (wr + f * 16 + l16) * 32 + lhi * 8);
    for (int f = 0; f < 4; ++f)
      bfr[f] = *(const bf16x8*)(Bsb + (wc + f * 16 + l16) * 32 + lhi * 8);
    for (int fm = 0; fm < 4; ++fm)
      for (int fn = 0; fn < 4; ++fn)
        acc[fm][fn] = __builtin_amdgcn_mfma_f32_16x16x32_bf16(af[fm], bfr[fn], acc[fm][fn], 0, 0, 0);
    buf ^= 1;
  }

  int slice = n0 >> 10;  // 0=q, 1=k, 2=v
  bool odd = l16 & 1;
  for (int fn = 0; fn < 4; ++fn) {
    int col = n0 + wc + fn * 16 + l16;
    int d = col & 1023;
    int h = d >> 6, hd = d & 63;
    float w = (slice == 0) ? __expf(NLOG4 * (float)(d & ~1) * (1.0f / 1024.0f)) : 0.f;
    for (int fm = 0; fm < 4; ++fm) {
      int row0 = m0 + wr + fm * 16 + lhi * 4;
      int t0 = row0 & 2047;
      for (int r = 0; r < 4; ++r) {
        size_t row = (size_t)(row0 + r);
        float v = acc[fm][fn][r];
        if (slice == 0) {
          float prt = __shfl_xor(v, 1);
          float si, co;
          __sincosf(w * (float)(t0 + r), &si, &co);
          float tr = odd ? (v * si - prt * co) : (v * si + prt * co);
          Qa[row * 2048 + h * 128 + hd] = f2bf(v * 0.125f);
          Qa[row * 2048 + h * 128 + 64 + hd] = f2bf(tr * 0.125f);
        } else if (slice == 1) {
          Ka[row * 2048 + h * 128 + hd] = f2bf(v);
        } else {
          Va[row * 1024 + h * 64 + hd] = f2bf(v);
        }
      }
    }
  }
}

// ---------------- bf16 GEMM (m97-style): C[M,N] = A[M,K] * BT[N,K]^T (+bias) ----------------
__global__ __launch_bounds__(256) void gemm_bf16(
    const ushort* __restrict__ A, const ushort* __restrict__ BT,
    float* __restrict__ C, const float* __restrict__ bias,
    int M, int N, int K) {
  __shared__ alignas(16) ushort As[2][4096];
  __shared__ alignas(16) ushort Bs[2][4096];
  int tid = threadIdx.x;
  int wave = tid >> 6, lane = tid & 63;
  int l16 = lane & 15, lhi = lane >> 4;
  int m0 = blockIdx.y * 128, n0 = blockIdx.x * 128;
  int wr = (wave >> 1) * 64, wc = (wave & 1) * 64;
  int srow = lane >> 2, sch = lane & 3;

  f32x4 acc[4][4] = {};

  auto stage = [&](int kk, int buf) {
    for (int i = 0; i < 2; ++i) {
      int rg = i * 4 + wave;
      g2l16(A + (size_t)(m0 + rg * 16 + srow) * K + kk + sch * 8, &As[buf][rg * 512]);
      g2l16(BT + (size_t)(n0 + rg * 16 + srow) * K + kk + sch * 8, &Bs[buf][rg * 512]);
    }
  };

  stage(0, 0);
  int buf = 0;
  for (int kk = 0; kk < K; kk += 32) {
    __syncthreads();
    if (kk + 32 < K) stage(kk + 32, buf ^ 1);
    const ushort* Asb = As[buf];
    const ushort* Bsb = Bs[buf];
    bf16x8 af[4], bfr[4];
    for (int f = 0; f < 4; ++f)
      af[f] = *(const bf16x8*)(Asb + (wr + f * 16 + l16) * 32 + lhi * 8);
    for (int f = 0; f < 4; ++f)
      bfr[f] = *(const bf16x8*)(Bsb + (wc + f * 16 + l16) * 32 + lhi * 8);
    for (int fm = 0; fm < 4; ++fm)
      for (int fn = 0; fn < 4; ++fn)
        acc[fm][fn] = __builtin_amdgcn_mfma_f32_16x16x32_bf16(af[fm], bfr[fn], acc[fm][fn], 0, 0, 0);
    buf ^= 1;
  }
  for (int fm = 0; fm < 4; ++fm)
    for (int fn = 0; fn < 4; ++fn)
      for (int r = 0; r < 4; ++r) {
        int row = m0 + wr + fm * 16 + lhi * 4 + r;
        int col = n0 + wc + fn * 16 + l16;
        float v = acc[fm][fn][r];
        if (bias) v += bias[col];
        C[(size_t)row * N + col] = v;
      }
}

// ---------------- transpose V: [B*T, H, 64] -> [BH, 64, T] ----------------
__global__ __launch_bounds__(256) void transpose_v(const ushort* __restrict__ Va,
                                                   ushort* __restrict__ Vt) {
  __shared__ ushort tile[64][72];
  int bh = blockIdx.y, t0 = blockIdx.x * 64;
  int b = bh >> 4, h = bh & 15;
  int tid = threadIdx.x;
  for (int i = 0; i < 2; ++i) {
    int e = tid + i * 256;
    int row = e >> 3, ch = e & 7;
    *(int4*)(&tile[row][ch * 8]) =
        *(const int4*)(Va + ((size_t)(b * T_ + t0 + row)) * 1024 + h * 64 + ch * 8);
  }
  __syncthreads();
  for (int i = 0; i < 2; ++i) {
    int e = tid + i * 256;
    int d = e >> 3, ch = e & 7;
    union { int4 v; ushort u[8]; } pk;
    for (int u = 0; u < 8; ++u) pk.u[u] = tile[ch * 8 + u][d];
    *(int4*)(Vt + ((size_t)bh * 64 + d) * T_ + t0 + ch * 8) = pk.v;
  }
}

// row-within-32 for 32x32 MFMA C/D layout
__device__ __forceinline__ int rowf32(int reg, int hi) {
  return (reg & 3) + 8 * (reg >> 2) + 4 * hi;
}

// ---------------- denominator kernel: 32x32 MFMA, quadrant waves ----------------
__global__ __launch_bounds__(256, 4) void denom_kernel(
    const ushort* __restrict__ Qa,  // [B*T, H, 128]
    const ushort* __restrict__ Ka,  // [B*T, H, 128]
    float* __restrict__ invlb) {    // [BH, T]
  int flat = blockIdx.y * 32 + blockIdx.x;
  int wg = (flat & 7) * 128 + (flat >> 3);
  int bh = wg >> 5;
  int qt = 31 - (wg & 31);
  int bb = bh >> 4, hh = bh & 15;
  int tid = threadIdx.x;
  int wave = tid >> 6, lane = tid & 63;
  int l31 = lane & 31, hi = lane >> 5;
  int r = wave >> 1, d = wave & 1;

  __shared__ alignas(16) ushort Ks[2][8192];  // [key 0..63][128], chunk^(key&15)
  __shared__ float sums[64];

  auto stageK = [&](int kt, int buf) {
    for (int i = 0; i < 4; ++i) {
      int rg = i * 4 + wave;
      int key = rg * 4 + (lane >> 4);
      const ushort* g = Ka + ((size_t)(bb * T_ + kt * 64 + key)) * 2048 + hh * 128 +
                        (((lane & 15) ^ (key & 15)) << 3);
      g2l16(g, &Ks[buf][rg * 512]);
    }
  };

  bf16x8 qf[8];
  {
    const ushort* Qg = Qa + ((size_t)(bb * T_ + qt * 64 + r * 32 + l31)) * 2048 + hh * 128;
    for (int ks = 0; ks < 8; ++ks)
      qf[ks] = *(const bf16x8*)(Qg + ks * 16 + hi * 8);
  }
  int key = d * 32 + l31;

  stageK(0, 0);
  asm volatile("s_waitcnt vmcnt(0)" ::: "memory");
  __builtin_amdgcn_s_barrier();
  float plsum[16];
  for (int i = 0; i < 16; ++i) plsum[i] = 0.f;

  for (int kt = 0; kt <= qt; ++kt) {
    int buf = kt & 1;
    if (kt < qt) stageK(kt + 1, buf ^ 1);
    __builtin_amdgcn_sched_barrier(0);
    const ushort* Kb = Ks[buf];
    f32x16 s = {};
    for (int ks = 0; ks < 8; ++ks) {
      int slot = (ks * 2 + hi) ^ (key & 15);
      bf16x8 kf = *(const bf16x8*)(Kb + key * 128 + (slot << 3));
      s = __builtin_amdgcn_mfma_f32_32x32x16_bf16(qf[ks], kf, s, 0, 0, 0);
    }
    if (kt == qt) {
      for (int reg = 0; reg < 16; ++reg)
        if (d * 32 + l31 > r * 32 + rowf32(reg, hi)) s[reg] = -1e30f;
    }
    for (int reg = 0; reg < 16; ++reg) plsum[reg] += __expf(s[reg]);
    if (kt < qt) {
      asm volatile("s_waitcnt vmcnt(0)" ::: "memory");
      __builtin_amdgcn_s_barrier();
    }
  }
  for (int reg = 0; reg < 16; ++reg) {
    float v = plsum[reg];
    for (int dd = 1; dd < 32; dd <<= 1) v += __shfl_xor(v, dd);
    plsum[reg] = v;
  }
  if (d == 1 && l31 == 0)
    for (int reg = 0; reg < 16; ++reg)
      sums[r * 32 + rowf32(reg, hi)] = plsum[reg];
  __syncthreads();
  if (d == 0 && l31 == 0)
    for (int reg = 0; reg < 16; ++reg) {
      int row = r * 32 + rowf32(reg, hi);
      invlb[(size_t)bh * T_ + qt * 64 + row] = 1.f / (plsum[reg] + sums[row]);
    }
}

// ---------------- attention main: 32x32 MFMA, quadrant waves ----------------
__global__ __launch_bounds__(256) void attn2_kernel(
    const ushort* __restrict__ Qa,    // [B*T, H, 128]
    const ushort* __restrict__ Ka,    // [B*T, H, 128]
    const ushort* __restrict__ Vt,    // [BH, 64, T]
    const float* __restrict__ invlb,  // [BH, T]
    float* __restrict__ score,        // [BH, T, T]
    ushort* __restrict__ ctxb) {      // [B*T, 1024] bf16
  int flat = blockIdx.y * 32 + blockIdx.x;
  int wg = (flat & 7) * 128 + (flat >> 3);
  int bh = wg >> 5;
  int qt = 31 - (wg & 31);
  int bb = bh >> 4, hh = bh & 15;
  int tid = threadIdx.x;
  int wave = tid >> 6, lane = tid & 63;
  int l31 = lane & 31, hi = lane >> 5;
  int r = wave >> 1, d = wave & 1;

  __shared__ alignas(16) ushort Ks[2][8192];  // [key][128], chunk^(key&15)
  __shared__ alignas(16) ushort Vs[2][4096];  // [dim][64 keys], chunk^(dim&7)
  __shared__ alignas(16) ushort Ps[4096];     // [qrow][64 keys], chunk^(row&7)

  const ushort* Vbase = Vt + (size_t)bh * 64 * T_;

  auto stageK = [&](int kt, int buf) {
    for (int i = 0; i < 4; ++i) {
      int rg = i * 4 + wave;
      int key = rg * 4 + (lane >> 4);
      const ushort* g = Ka + ((size_t)(bb * T_ + kt * 64 + key)) * 2048 + hh * 128 +
                        (((lane & 15) ^ (key & 15)) << 3);
      g2l16(g, &Ks[buf][rg * 512]);
    }
  };
  auto stageV = [&](int kt, int buf) {
    for (int i = 0; i < 2; ++i) {
      int rg = i * 4 + wave;
      int dim = rg * 8 + (lane >> 3);
      const ushort* g = Vbase + (size_t)dim * T_ + kt * 64 + (((lane & 7) ^ (dim & 7)) << 3);
      g2l16(g, &Vs[buf][rg * 512]);
    }
  };

  bf16x8 qf[8];
  {
    const ushort* Qg = Qa + ((size_t)(bb * T_ + qt * 64 + r * 32 + l31)) * 2048 + hh * 128;
    for (int ks = 0; ks < 8; ++ks)
      qf[ks] = *(const bf16x8*)(Qg + ks * 16 + hi * 8);
  }
  int key = d * 32 + l31;
  float4 iv[4];
  for (int g = 0; g < 4; ++g)
    iv[g] = *(const float4*)(invlb + (size_t)bh * T_ + qt * 64 + r * 32 + hi * 4 + g * 8);

  stageK(0, 0);
  stageV(0, 0);
  asm volatile("s_waitcnt vmcnt(0)" ::: "memory");
  __builtin_amdgcn_s_barrier();
  f32x16 cacc[2] = {};
  float* srow = score + ((size_t)bh * T_ + (size_t)qt * 64) * T_;

  for (int kt = 0; kt <= qt; ++kt) {
    int buf = kt & 1;
    if (kt < qt) { stageK(kt + 1, buf ^ 1); stageV(kt + 1, buf ^ 1); }
    __builtin_amdgcn_sched_barrier(0);
    const ushort* Kb = Ks[buf];
    f32x16 s = {};
    for (int ks = 0; ks < 8; ++ks) {
      int slot = (ks * 2 + hi) ^ (key & 15);
      bf16x8 kf = *(const bf16x8*)(Kb + key * 128 + (slot << 3));
      s = __builtin_amdgcn_mfma_f32_32x32x16_bf16(qf[ks], kf, s, 0, 0, 0);
    }
    if (kt == qt) {
      for (int reg = 0; reg < 16; ++reg)
        if (d * 32 + l31 > r * 32 + rowf32(reg, hi)) s[reg] = -1e30f;
    }
    for (int reg = 0; reg < 16; ++reg) {
      int row_loc = r * 32 + rowf32(reg, hi);
      float p = __expf(s[reg]) * iv[reg >> 2][reg & 3];
      srow[(size_t)row_loc * T_ + kt * 64 + key] = p;
      Ps[row_loc * 64 + ((((key >> 3)) ^ (row_loc & 7)) << 3) + (key & 7)] = f2bf(p);
    }
    asm volatile("s_waitcnt lgkmcnt(0)" ::: "memory");
    __builtin_amdgcn_sched_barrier(0);
    const ushort* Vb2 = Vs[buf];
    int rowA = r * 32 + l31;
    for (int ks2 = 0; ks2 < 2; ++ks2) {
      int chunkA = d * 4 + ks2 * 2 + hi;
      bf16x8 pa = *(const bf16x8*)(Ps + rowA * 64 + ((chunkA ^ (rowA & 7)) << 3));
      for (int b2 = 0; b2 < 2; ++b2) {
        int dim = b2 * 32 + l31;
        bf16x8 vb = *(const bf16x8*)(Vb2 + dim * 64 + ((chunkA ^ (dim & 7)) << 3));
        cacc[b2] = __builtin_amdgcn_mfma_f32_32x32x16_bf16(pa, vb, cacc[b2], 0, 0, 0);
      }
    }
    if (kt < qt) {
      asm volatile("s_waitcnt vmcnt(16)" ::: "memory");
      __builtin_amdgcn_s_barrier();
    }
  }

  // zero-fill upper-triangle tiles of score
  {
    int row = tid >> 2, c16 = (tid & 3) * 16;
    f32x4 z = {0.f, 0.f, 0.f, 0.f};
    for (int kt = qt + 1; kt < 32; ++kt) {
      f32x4* dst = (f32x4*)(srow + (size_t)row * T_ + kt * 64 + c16);
      for (int u = 0; u < 4; ++u) dst[u] = z;
    }
  }

  // combine key-half partial ctx across wave pairs, write ctxb
  __builtin_amdgcn_s_barrier();
  float* xch = (float*)Ks;
  if (d == 1) {
    for (int b2 = 0; b2 < 2; ++b2)
      for (int reg = 0; reg < 16; ++reg)
        xch[(r * 32 + rowf32(reg, hi)) * 64 + b2 * 32 + l31] = cacc[b2][reg];
  }
  __syncthreads();
  if (d == 0) {
    for (int b2 = 0; b2 < 2; ++b2)
      for (int reg = 0; reg < 16; ++reg) {
        int row_loc = r * 32 + rowf32(reg, hi);
        float v = cacc[b2][reg] + xch[row_loc * 64 + b2 * 32 + l31];
        int t = qt * 64 + row_loc;
        ctxb[((size_t)(bb * T_ + t)) * 1024 + hh * 64 + b2 * 32 + l31] = f2bf(v);
      }
  }
}

extern "C" void kernel_launch(void* const* d_in, const int* in_sizes, int n_in,
                              void* d_out, int out_size, void* d_ws, size_t ws_size,
                              hipStream_t stream) {
  const float* x    = (const float*)d_in[0];
  const float* Wqkv = (const float*)d_in[2];
  const float* Wout = (const float*)d_in[3];
  const float* bout = (const float*)d_in[4];

  char* ws = (char*)d_ws;
  ushort* xb    = (ushort*)(ws + 0);          //  8 MB
  ushort* wqkvT = (ushort*)(ws + 8388608);    //  6 MB
  ushort* woutT = (ushort*)(ws + 14680064);   //  2 MB
  ushort* Qa    = (ushort*)(ws + 16777216);   // 16 MB  [B*T,H,128]
  ushort* Ka    = (ushort*)(ws + 33554432);   // 16 MB  [B*T,H,128]
  ushort* Va    = (ushort*)(ws + 50331648);   //  8 MB  [B*T,H,64]
  ushort* Vt    = (ushort*)(ws + 58720256);   //  8 MB  [BH,64,T]
  ushort* ctxb  = (ushort*)(ws + 67108864);   //  8 MB
  float*  invlb = (float*) (ws + 75497472);   // 256 KB

  float* out   = (float*)d_out;
  float* score = out + (size_t)4194304;  // B*T*D floats, then [B,H,T,T]

  cvt_kernel<<<4096, 256, 0, stream>>>(x, xb);
  dim3 tb(32, 8);
  transpose_cvt<<<dim3(3072 / 32, 1024 / 32), tb, 0, stream>>>(Wqkv, wqkvT, 1024, 3072);
  transpose_cvt<<<dim3(1024 / 32, 1024 / 32), tb, 0, stream>>>(Wout, woutT, 1024, 1024);
  fill_ktrig<<<2048, 512, 0, stream>>>(Ka);
  gemm_qkv<<<dim3(24, 32), 256, 0, stream>>>(xb, wqkvT, Qa, Ka, Va);
  transpose_v<<<dim3(32, 32), 256, 0, stream>>>(Va, Vt);
  denom_kernel<<<dim3(32, 32), 256, 0, stream>>>(Qa, Ka, invlb);
  attn2_kernel<<<dim3(32, 32), 256, 0, stream>>>(Qa, Ka, Vt, invlb, score, ctxb);
  gemm_bf16<<<dim3(8, 32), 256, 0, stream>>>(ctxb, woutT, out, bout, 4096, 1024, 1024);
}

// Round 17
// 346.528 us; speedup vs baseline: 1.9773x; 1.9773x over previous
//
#include <hip/hip_runtime.h>

typedef __bf16 bf16x8 __attribute__((ext_vector_type(8)));
typedef float f32x4 __attribute__((ext_vector_type(4)));
typedef float f32x16 __attribute__((ext_vector_type(16)));

#define B_ 2
#define T_ 2048
#define D_ 1024
#define H_ 16

__device__ __forceinline__ ushort f2bf(float f) {
  union { float f; unsigned u; } v; v.f = f;
  unsigned u = v.u;
  return (ushort)((u + 0x7FFFu + ((u >> 16) & 1u)) >> 16);
}

// async global->LDS, 16B per lane; LDS dest is wave-uniform base + lane*16
__device__ __forceinline__ void g2l16(const void* g, void* l) {
  __builtin_amdgcn_global_load_lds(
      (const __attribute__((address_space(1))) unsigned int*)g,
      (__attribute__((address_space(3))) unsigned int*)l, 16, 0, 0);
}

// ---------------- cast x -> bf16 ----------------
__global__ __launch_bounds__(256) void cvt_kernel(const float* __restrict__ in,
                                                  ushort* __restrict__ out) {
  int i = (blockIdx.x * 256 + threadIdx.x) * 4;
  float4 v = *(const float4*)(in + i);
  ushort4 o;
  o.x = f2bf(v.x); o.y = f2bf(v.y); o.z = f2bf(v.z); o.w = f2bf(v.w);
  *(ushort4*)(out + i) = o;
}

// ---------------- transpose + cast: in[R][C] f32 -> out[C][R] bf16 ----------------
__global__ void transpose_cvt(const float* __restrict__ in, ushort* __restrict__ out,
                              int R, int C) {
  __shared__ float tile[32][33];
  int bx = blockIdx.x * 32, by = blockIdx.y * 32;
  int tx = threadIdx.x, ty = threadIdx.y;  // block (32,8)
  for (int i = 0; i < 32; i += 8)
    tile[ty + i][tx] = in[(size_t)(by + ty + i) * C + (bx + tx)];
  __syncthreads();
  for (int i = 0; i < 32; i += 8)
    out[(size_t)(bx + ty + i) * R + (by + tx)] = f2bf(tile[tx][ty + i]);
}

// ---------------- bf16 GEMM (m97-style): C[M,N] = A[M,K] * BT[N,K]^T (+bias) ----------------
__global__ __launch_bounds__(256) void gemm_bf16(
    const ushort* __restrict__ A, const ushort* __restrict__ BT,
    float* __restrict__ C, const float* __restrict__ bias,
    int M, int N, int K) {
  __shared__ alignas(16) ushort As[2][4096];
  __shared__ alignas(16) ushort Bs[2][4096];
  int tid = threadIdx.x;
  int wave = tid >> 6, lane = tid & 63;
  int l16 = lane & 15, lhi = lane >> 4;
  int m0 = blockIdx.y * 128, n0 = blockIdx.x * 128;
  int wr = (wave >> 1) * 64, wc = (wave & 1) * 64;
  int srow = lane >> 2, sch = lane & 3;

  f32x4 acc[4][4] = {};

  auto stage = [&](int kk, int buf) {
    for (int i = 0; i < 2; ++i) {
      int rg = i * 4 + wave;
      g2l16(A + (size_t)(m0 + rg * 16 + srow) * K + kk + sch * 8, &As[buf][rg * 512]);
      g2l16(BT + (size_t)(n0 + rg * 16 + srow) * K + kk + sch * 8, &Bs[buf][rg * 512]);
    }
  };

  stage(0, 0);
  int buf = 0;
  for (int kk = 0; kk < K; kk += 32) {
    __syncthreads();
    if (kk + 32 < K) stage(kk + 32, buf ^ 1);
    const ushort* Asb = As[buf];
    const ushort* Bsb = Bs[buf];
    bf16x8 af[4], bfr[4];
    for (int f = 0; f < 4; ++f)
      af[f] = *(const bf16x8*)(Asb + (wr + f * 16 + l16) * 32 + lhi * 8);
    for (int f = 0; f < 4; ++f)
      bfr[f] = *(const bf16x8*)(Bsb + (wc + f * 16 + l16) * 32 + lhi * 8);
    for (int fm = 0; fm < 4; ++fm)
      for (int fn = 0; fn < 4; ++fn)
        acc[fm][fn] = __builtin_amdgcn_mfma_f32_16x16x32_bf16(af[fm], bfr[fn], acc[fm][fn], 0, 0, 0);
    buf ^= 1;
  }
  for (int fm = 0; fm < 4; ++fm)
    for (int fn = 0; fn < 4; ++fn)
      for (int r = 0; r < 4; ++r) {
        int row = m0 + wr + fm * 16 + lhi * 4 + r;
        int col = n0 + wc + fn * 16 + l16;
        float v = acc[fm][fn][r];
        if (bias) v += bias[col];
        C[(size_t)row * N + col] = v;
      }
}

// ---------------- build Qaug/Kaug/V from qkv ----------------
__global__ __launch_bounds__(256) void augment_kernel(
    const float* __restrict__ qkv,  // [B*T, 3072]
    ushort* __restrict__ Qaug, ushort* __restrict__ Kaug, ushort* __restrict__ Vb) {
  int row = blockIdx.x;
  int b = row >> 11;
  int t = row & 2047;
  int tid = threadIdx.x;
  const float* src = qkv + (size_t)row * 3072;
  for (int i = 0; i < 4; ++i) {
    int idx = tid + i * 256;
    int h = idx >> 6, d = idx & 63;
    size_t obase = ((size_t)(b * H_ + h) * T_ + t);
    float q = src[idx];
    float k = src[1024 + idx];
    float v = src[2048 + idx];
    Qaug[obase * 128 + d] = f2bf(q * 0.125f);
    Kaug[obase * 128 + d] = f2bf(k);
    Vb[obase * 64 + d] = f2bf(v);
  }
  for (int i = 0; i < 2; ++i) {
    int idx = tid + i * 256;
    int h = idx >> 5, mm = idx & 31;
    int gdim = h * 64 + 2 * mm;
    float w = __expf(-9.2103403719761836f * (float)gdim * (1.0f / 1024.0f));
    float ang = w * (float)t;
    float si, co;
    __sincosf(ang, &si, &co);
    float qs = src[h * 64 + 2 * mm], qc = src[h * 64 + 2 * mm + 1];
    size_t obase = ((size_t)(b * H_ + h) * T_ + t);
    Qaug[obase * 128 + 64 + 2 * mm]     = f2bf((qs * si + qc * co) * 0.125f);
    Qaug[obase * 128 + 64 + 2 * mm + 1] = f2bf((qc * si - qs * co) * 0.125f);
    Kaug[obase * 128 + 64 + 2 * mm]     = f2bf(co);
    Kaug[obase * 128 + 64 + 2 * mm + 1] = f2bf(si);
  }
}

// ---------------- transpose V: [BH, T, 64] -> [BH, 64, T] ----------------
__global__ __launch_bounds__(256) void transpose_v(const ushort* __restrict__ Vb,
                                                   ushort* __restrict__ Vt) {
  __shared__ ushort tile[64][72];
  int bh = blockIdx.y, t0 = blockIdx.x * 64;
  int tid = threadIdx.x;
  for (int i = 0; i < 2; ++i) {
    int e = tid + i * 256;
    int row = e >> 3, ch = e & 7;
    *(int4*)(&tile[row][ch * 8]) =
        *(const int4*)(Vb + ((size_t)bh * T_ + t0 + row) * 64 + ch * 8);
  }
  __syncthreads();
  for (int i = 0; i < 2; ++i) {
    int e = tid + i * 256;
    int d = e >> 3, ch = e & 7;
    union { int4 v; ushort u[8]; } pk;
    for (int u = 0; u < 8; ++u) pk.u[u] = tile[ch * 8 + u][d];
    *(int4*)(Vt + ((size_t)bh * 64 + d) * T_ + t0 + ch * 8) = pk.v;
  }
}

// row-within-32 for 32x32 MFMA C/D layout
__device__ __forceinline__ int rowf32(int reg, int hi) {
  return (reg & 3) + 8 * (reg >> 2) + 4 * hi;
}

// ---------------- denominator kernel: 32x32 MFMA, split accumulator chains ----------------
__global__ __launch_bounds__(256, 4) void denom_kernel(
    const ushort* __restrict__ Qaug,  // [BH, T, 128]
    const ushort* __restrict__ Kaug,  // [BH, T, 128]
    float* __restrict__ invlb) {      // [BH, T]
  int flat = blockIdx.y * 32 + blockIdx.x;
  int wg = (flat & 7) * 128 + (flat >> 3);
  int bh = wg >> 5;
  int qt = 31 - (wg & 31);
  int tid = threadIdx.x;
  int wave = tid >> 6, lane = tid & 63;
  int l31 = lane & 31, hi = lane >> 5;
  int r = wave >> 1, d = wave & 1;

  __shared__ alignas(16) ushort Ks[2][8192];  // [key 0..63][128], chunk^(key&15)
  __shared__ float sums[64];

  const ushort* Kbase = Kaug + (size_t)bh * T_ * 128;

  auto stageK = [&](int kt, int buf) {
    for (int i = 0; i < 4; ++i) {
      int rg = i * 4 + wave;
      int key = rg * 4 + (lane >> 4);
      const ushort* g = Kbase + ((size_t)(kt * 64 + key)) * 128 + (((lane & 15) ^ (key & 15)) << 3);
      g2l16(g, &Ks[buf][rg * 512]);
    }
  };

  bf16x8 qf[8];
  {
    const ushort* Qg = Qaug + ((size_t)bh * T_ + qt * 64 + r * 32 + l31) * 128;
    for (int ks = 0; ks < 8; ++ks)
      qf[ks] = *(const bf16x8*)(Qg + ks * 16 + hi * 8);
  }
  int key = d * 32 + l31;

  stageK(0, 0);
  asm volatile("s_waitcnt vmcnt(0)" ::: "memory");
  __builtin_amdgcn_s_barrier();
  float plsum[16];
  for (int i = 0; i < 16; ++i) plsum[i] = 0.f;

  for (int kt = 0; kt <= qt; ++kt) {
    int buf = kt & 1;
    if (kt < qt) stageK(kt + 1, buf ^ 1);
    __builtin_amdgcn_sched_barrier(0);
    const ushort* Kb = Ks[buf];
    f32x16 s0 = {}, s1 = {};  // 2-way split accumulator chain (MFMA ILP)
    for (int ks = 0; ks < 8; ks += 2) {
      int slotA = (ks * 2 + hi) ^ (key & 15);
      bf16x8 kfA = *(const bf16x8*)(Kb + key * 128 + (slotA << 3));
      s0 = __builtin_amdgcn_mfma_f32_32x32x16_bf16(qf[ks], kfA, s0, 0, 0, 0);
      int slotB = ((ks + 1) * 2 + hi) ^ (key & 15);
      bf16x8 kfB = *(const bf16x8*)(Kb + key * 128 + (slotB << 3));
      s1 = __builtin_amdgcn_mfma_f32_32x32x16_bf16(qf[ks + 1], kfB, s1, 0, 0, 0);
    }
    f32x16 s = s0 + s1;
    if (kt == qt) {
      for (int reg = 0; reg < 16; ++reg)
        if (d * 32 + l31 > r * 32 + rowf32(reg, hi)) s[reg] = -1e30f;
    }
    for (int reg = 0; reg < 16; ++reg) plsum[reg] += __expf(s[reg]);
    if (kt < qt) {
      asm volatile("s_waitcnt vmcnt(0)" ::: "memory");
      __builtin_amdgcn_s_barrier();
    }
  }
  for (int reg = 0; reg < 16; ++reg) {
    float v = plsum[reg];
    for (int dd = 1; dd < 32; dd <<= 1) v += __shfl_xor(v, dd);
    plsum[reg] = v;
  }
  if (d == 1 && l31 == 0)
    for (int reg = 0; reg < 16; ++reg)
      sums[r * 32 + rowf32(reg, hi)] = plsum[reg];
  __syncthreads();
  if (d == 0 && l31 == 0)
    for (int reg = 0; reg < 16; ++reg) {
      int row = r * 32 + rowf32(reg, hi);
      invlb[(size_t)bh * T_ + qt * 64 + row] = 1.f / (plsum[reg] + sums[row]);
    }
}

// ---------------- attention main: 32x32 MFMA, split accumulator chains ----------------
__global__ __launch_bounds__(256) void attn2_kernel(
    const ushort* __restrict__ Qaug,  // [BH, T, 128]
    const ushort* __restrict__ Kaug,  // [BH, T, 128]
    const ushort* __restrict__ Vt,    // [BH, 64, T]
    const float* __restrict__ invlb,  // [BH, T]
    float* __restrict__ score,        // [BH, T, T]
    ushort* __restrict__ ctxb) {      // [B*T, 1024] bf16
  int flat = blockIdx.y * 32 + blockIdx.x;
  int wg = (flat & 7) * 128 + (flat >> 3);
  int bh = wg >> 5;
  int qt = 31 - (wg & 31);
  int tid = threadIdx.x;
  int wave = tid >> 6, lane = tid & 63;
  int l31 = lane & 31, hi = lane >> 5;
  int r = wave >> 1, d = wave & 1;

  __shared__ alignas(16) ushort Ks[2][8192];  // [key][128], chunk^(key&15)
  __shared__ alignas(16) ushort Vs[2][4096];  // [dim][64 keys], chunk^(dim&7)
  __shared__ alignas(16) ushort Ps[4096];     // [qrow][64 keys], chunk^(row&7)

  const ushort* Kbase = Kaug + (size_t)bh * T_ * 128;
  const ushort* Vbase = Vt + (size_t)bh * 64 * T_;

  auto stageK = [&](int kt, int buf) {
    for (int i = 0; i < 4; ++i) {
      int rg = i * 4 + wave;
      int key = rg * 4 + (lane >> 4);
      const ushort* g = Kbase + ((size_t)(kt * 64 + key)) * 128 + (((lane & 15) ^ (key & 15)) << 3);
      g2l16(g, &Ks[buf][rg * 512]);
    }
  };
  auto stageV = [&](int kt, int buf) {
    for (int i = 0; i < 2; ++i) {
      int rg = i * 4 + wave;
      int dim = rg * 8 + (lane >> 3);
      const ushort* g = Vbase + (size_t)dim * T_ + kt * 64 + (((lane & 7) ^ (dim & 7)) << 3);
      g2l16(g, &Vs[buf][rg * 512]);
    }
  };

  bf16x8 qf[8];
  {
    const ushort* Qg = Qaug + ((size_t)bh * T_ + qt * 64 + r * 32 + l31) * 128;
    for (int ks = 0; ks < 8; ++ks)
      qf[ks] = *(const bf16x8*)(Qg + ks * 16 + hi * 8);
  }
  int key = d * 32 + l31;
  float4 iv[4];
  for (int g = 0; g < 4; ++g)
    iv[g] = *(const float4*)(invlb + (size_t)bh * T_ + qt * 64 + r * 32 + hi * 4 + g * 8);

  stageK(0, 0);
  stageV(0, 0);
  asm volatile("s_waitcnt vmcnt(0)" ::: "memory");
  __builtin_amdgcn_s_barrier();
  f32x16 cacc[2] = {};
  float* srow = score + ((size_t)bh * T_ + (size_t)qt * 64) * T_;

  for (int kt = 0; kt <= qt; ++kt) {
    int buf = kt & 1;
    if (kt < qt) { stageK(kt + 1, buf ^ 1); stageV(kt + 1, buf ^ 1); }
    __builtin_amdgcn_sched_barrier(0);
    const ushort* Kb = Ks[buf];
    f32x16 s0 = {}, s1 = {};  // 2-way split accumulator chain (MFMA ILP)
    for (int ks = 0; ks < 8; ks += 2) {
      int slotA = (ks * 2 + hi) ^ (key & 15);
      bf16x8 kfA = *(const bf16x8*)(Kb + key * 128 + (slotA << 3));
      s0 = __builtin_amdgcn_mfma_f32_32x32x16_bf16(qf[ks], kfA, s0, 0, 0, 0);
      int slotB = ((ks + 1) * 2 + hi) ^ (key & 15);
      bf16x8 kfB = *(const bf16x8*)(Kb + key * 128 + (slotB << 3));
      s1 = __builtin_amdgcn_mfma_f32_32x32x16_bf16(qf[ks + 1], kfB, s1, 0, 0, 0);
    }
    f32x16 s = s0 + s1;
    if (kt == qt) {
      for (int reg = 0; reg < 16; ++reg)
        if (d * 32 + l31 > r * 32 + rowf32(reg, hi)) s[reg] = -1e30f;
    }
    for (int reg = 0; reg < 16; ++reg) {
      int row_loc = r * 32 + rowf32(reg, hi);
      float p = __expf(s[reg]) * iv[reg >> 2][reg & 3];
      srow[(size_t)row_loc * T_ + kt * 64 + key] = p;
      Ps[row_loc * 64 + ((((key >> 3)) ^ (row_loc & 7)) << 3) + (key & 7)] = f2bf(p);
    }
    asm volatile("s_waitcnt lgkmcnt(0)" ::: "memory");
    __builtin_amdgcn_sched_barrier(0);
    const ushort* Vb2 = Vs[buf];
    int rowA = r * 32 + l31;
    for (int ks2 = 0; ks2 < 2; ++ks2) {
      int chunkA = d * 4 + ks2 * 2 + hi;
      bf16x8 pa = *(const bf16x8*)(Ps + rowA * 64 + ((chunkA ^ (rowA & 7)) << 3));
      for (int b2 = 0; b2 < 2; ++b2) {
        int dim = b2 * 32 + l31;
        bf16x8 vb = *(const bf16x8*)(Vb2 + dim * 64 + ((chunkA ^ (dim & 7)) << 3));
        cacc[b2] = __builtin_amdgcn_mfma_f32_32x32x16_bf16(pa, vb, cacc[b2], 0, 0, 0);
      }
    }
    if (kt < qt) {
      asm volatile("s_waitcnt vmcnt(16)" ::: "memory");
      __builtin_amdgcn_s_barrier();
    }
  }

  // zero-fill upper-triangle tiles of score
  {
    int row = tid >> 2, c16 = (tid & 3) * 16;
    f32x4 z = {0.f, 0.f, 0.f, 0.f};
    for (int kt = qt + 1; kt < 32; ++kt) {
      f32x4* dst = (f32x4*)(srow + (size_t)row * T_ + kt * 64 + c16);
      for (int u = 0; u < 4; ++u) dst[u] = z;
    }
  }

  // combine key-half partial ctx across wave pairs, write ctxb
  __builtin_amdgcn_s_barrier();
  float* xch = (float*)Ks;
  if (d == 1) {
    for (int b2 = 0; b2 < 2; ++b2)
      for (int reg = 0; reg < 16; ++reg)
        xch[(r * 32 + rowf32(reg, hi)) * 64 + b2 * 32 + l31] = cacc[b2][reg];
  }
  __syncthreads();
  if (d == 0) {
    int b = bh >> 4, h = bh & 15;
    for (int b2 = 0; b2 < 2; ++b2)
      for (int reg = 0; reg < 16; ++reg) {
        int row_loc = r * 32 + rowf32(reg, hi);
        float v = cacc[b2][reg] + xch[row_loc * 64 + b2 * 32 + l31];
        int t = qt * 64 + row_loc;
        ctxb[((size_t)(b * T_ + t)) * 1024 + h * 64 + b2 * 32 + l31] = f2bf(v);
      }
  }
}

extern "C" void kernel_launch(void* const* d_in, const int* in_sizes, int n_in,
                              void* d_out, int out_size, void* d_ws, size_t ws_size,
                              hipStream_t stream) {
  const float* x    = (const float*)d_in[0];
  const float* Wqkv = (const float*)d_in[2];
  const float* Wout = (const float*)d_in[3];
  const float* bout = (const float*)d_in[4];

  char* ws = (char*)d_ws;
  ushort* xb    = (ushort*)(ws + 0);           //  8 MB
  ushort* wqkvT = (ushort*)(ws + 8388608);     //  6 MB
  ushort* woutT = (ushort*)(ws + 14680064);    //  2 MB
  float*  qkv   = (float*) (ws + 16777216);    // 48 MB (dead after augment)
  ushort* Qaug  = (ushort*)(ws + 67108864);    // 16 MB
  ushort* Kaug  = (ushort*)(ws + 83886080);    // 16 MB
  ushort* Vb    = (ushort*)(ws + 100663296);   //  8 MB
  ushort* ctxb  = (ushort*)(ws + 109051904);   //  8 MB
  ushort* Vt    = (ushort*)(ws + 16777216);    //  8 MB, overlaps dead qkv
  float*  invlb = (float*) (ws + 25165824);    // 256 KB, after Vt in dead-qkv region

  float* out   = (float*)d_out;
  float* score = out + (size_t)4194304;  // B*T*D floats, then [B,H,T,T]

  cvt_kernel<<<4096, 256, 0, stream>>>(x, xb);
  dim3 tb(32, 8);
  transpose_cvt<<<dim3(3072 / 32, 1024 / 32), tb, 0, stream>>>(Wqkv, wqkvT, 1024, 3072);
  transpose_cvt<<<dim3(1024 / 32, 1024 / 32), tb, 0, stream>>>(Wout, woutT, 1024, 1024);
  gemm_bf16<<<dim3(24, 32), 256, 0, stream>>>(xb, wqkvT, qkv, nullptr, 4096, 3072, 1024);
  augment_kernel<<<4096, 256, 0, stream>>>(qkv, Qaug, Kaug, Vb);
  transpose_v<<<dim3(32, 32), 256, 0, stream>>>(Vb, Vt);
  denom_kernel<<<dim3(32, 32), 256, 0, stream>>>(Qaug, Kaug, invlb);
  attn2_kernel<<<dim3(32, 32), 256, 0, stream>>>(Qaug, Kaug, Vt, invlb, score, ctxb);
  gemm_bf16<<<dim3(8, 32), 256, 0, stream>>>(ctxb, woutT, out, bout, 4096, 1024, 1024);
}

// Round 18
// 314.647 us; speedup vs baseline: 2.1776x; 1.1013x over previous
//
#include <hip/hip_runtime.h>

typedef __bf16 bf16x8 __attribute__((ext_vector_type(8)));
typedef float f32x4 __attribute__((ext_vector_type(4)));
typedef float f32x16 __attribute__((ext_vector_type(16)));

#define B_ 2
#define T_ 2048
#define D_ 1024
#define H_ 16

__device__ __forceinline__ ushort f2bf(float f) {
  union { float f; unsigned u; } v; v.f = f;
  unsigned u = v.u;
  return (ushort)((u + 0x7FFFu + ((u >> 16) & 1u)) >> 16);
}
__device__ __forceinline__ float b2f(ushort u) {
  union { unsigned u; float f; } v; v.u = ((unsigned)u) << 16;
  return v.f;
}

// async global->LDS, 16B per lane; LDS dest is wave-uniform base + lane*16
__device__ __forceinline__ void g2l16(const void* g, void* l) {
  __builtin_amdgcn_global_load_lds(
      (const __attribute__((address_space(1))) unsigned int*)g,
      (__attribute__((address_space(3))) unsigned int*)l, 16, 0, 0);
}

// ---------------- cast x -> bf16 ----------------
__global__ __launch_bounds__(256) void cvt_kernel(const float* __restrict__ in,
                                                  ushort* __restrict__ out) {
  int i = (blockIdx.x * 256 + threadIdx.x) * 4;
  float4 v = *(const float4*)(in + i);
  ushort4 o;
  o.x = f2bf(v.x); o.y = f2bf(v.y); o.z = f2bf(v.z); o.w = f2bf(v.w);
  *(ushort4*)(out + i) = o;
}

// ---------------- transpose + cast: in[R][C] f32 -> out[C][R] bf16 ----------------
__global__ void transpose_cvt(const float* __restrict__ in, ushort* __restrict__ out,
                              int R, int C) {
  __shared__ float tile[32][33];
  int bx = blockIdx.x * 32, by = blockIdx.y * 32;
  int tx = threadIdx.x, ty = threadIdx.y;  // block (32,8)
  for (int i = 0; i < 32; i += 8)
    tile[ty + i][tx] = in[(size_t)(by + ty + i) * C + (bx + tx)];
  __syncthreads();
  for (int i = 0; i < 32; i += 8)
    out[(size_t)(bx + ty + i) * R + (by + tx)] = f2bf(tile[tx][ty + i]);
}

// ---------------- bf16 GEMM, f32 out (+bias) ----------------
__global__ __launch_bounds__(256) void gemm_bf16(
    const ushort* __restrict__ A, const ushort* __restrict__ BT,
    float* __restrict__ C, const float* __restrict__ bias,
    int M, int N, int K) {
  __shared__ alignas(16) ushort As[2][4096];
  __shared__ alignas(16) ushort Bs[2][4096];
  int tid = threadIdx.x;
  int wave = tid >> 6, lane = tid & 63;
  int l16 = lane & 15, lhi = lane >> 4;
  int m0 = blockIdx.y * 128, n0 = blockIdx.x * 128;
  int wr = (wave >> 1) * 64, wc = (wave & 1) * 64;
  int srow = lane >> 2, sch = lane & 3;

  f32x4 acc[4][4] = {};

  auto stage = [&](int kk, int buf) {
    for (int i = 0; i < 2; ++i) {
      int rg = i * 4 + wave;
      g2l16(A + (size_t)(m0 + rg * 16 + srow) * K + kk + sch * 8, &As[buf][rg * 512]);
      g2l16(BT + (size_t)(n0 + rg * 16 + srow) * K + kk + sch * 8, &Bs[buf][rg * 512]);
    }
  };

  stage(0, 0);
  int buf = 0;
  for (int kk = 0; kk < K; kk += 32) {
    __syncthreads();
    if (kk + 32 < K) stage(kk + 32, buf ^ 1);
    const ushort* Asb = As[buf];
    const ushort* Bsb = Bs[buf];
    bf16x8 af[4], bfr[4];
    for (int f = 0; f < 4; ++f)
      af[f] = *(const bf16x8*)(Asb + (wr + f * 16 + l16) * 32 + lhi * 8);
    for (int f = 0; f < 4; ++f)
      bfr[f] = *(const bf16x8*)(Bsb + (wc + f * 16 + l16) * 32 + lhi * 8);
    for (int fm = 0; fm < 4; ++fm)
      for (int fn = 0; fn < 4; ++fn)
        acc[fm][fn] = __builtin_amdgcn_mfma_f32_16x16x32_bf16(af[fm], bfr[fn], acc[fm][fn], 0, 0, 0);
    buf ^= 1;
  }
  for (int fm = 0; fm < 4; ++fm)
    for (int fn = 0; fn < 4; ++fn)
      for (int r = 0; r < 4; ++r) {
        int row = m0 + wr + fm * 16 + lhi * 4 + r;
        int col = n0 + wc + fn * 16 + l16;
        float v = acc[fm][fn][r];
        if (bias) v += bias[col];
        C[(size_t)row * N + col] = v;
      }
}

// ---------------- bf16 GEMM, bf16 out (row-major, line-assembled stores) ----------------
__global__ __launch_bounds__(256) void gemm_bf16_ob(
    const ushort* __restrict__ A, const ushort* __restrict__ BT,
    ushort* __restrict__ C, int M, int N, int K) {
  __shared__ alignas(16) ushort As[2][4096];
  __shared__ alignas(16) ushort Bs[2][4096];
  int tid = threadIdx.x;
  int wave = tid >> 6, lane = tid & 63;
  int l16 = lane & 15, lhi = lane >> 4;
  int m0 = blockIdx.y * 128, n0 = blockIdx.x * 128;
  int wr = (wave >> 1) * 64, wc = (wave & 1) * 64;
  int srow = lane >> 2, sch = lane & 3;

  f32x4 acc[4][4] = {};

  auto stage = [&](int kk, int buf) {
    for (int i = 0; i < 2; ++i) {
      int rg = i * 4 + wave;
      g2l16(A + (size_t)(m0 + rg * 16 + srow) * K + kk + sch * 8, &As[buf][rg * 512]);
      g2l16(BT + (size_t)(n0 + rg * 16 + srow) * K + kk + sch * 8, &Bs[buf][rg * 512]);
    }
  };

  stage(0, 0);
  int buf = 0;
  for (int kk = 0; kk < K; kk += 32) {
    __syncthreads();
    if (kk + 32 < K) stage(kk + 32, buf ^ 1);
    const ushort* Asb = As[buf];
    const ushort* Bsb = Bs[buf];
    bf16x8 af[4], bfr[4];
    for (int f = 0; f < 4; ++f)
      af[f] = *(const bf16x8*)(Asb + (wr + f * 16 + l16) * 32 + lhi * 8);
    for (int f = 0; f < 4; ++f)
      bfr[f] = *(const bf16x8*)(Bsb + (wc + f * 16 + l16) * 32 + lhi * 8);
    for (int fm = 0; fm < 4; ++fm)
      for (int fn = 0; fn < 4; ++fn)
        acc[fm][fn] = __builtin_amdgcn_mfma_f32_16x16x32_bf16(af[fm], bfr[fn], acc[fm][fn], 0, 0, 0);
    buf ^= 1;
  }
  for (int fm = 0; fm < 4; ++fm)
    for (int fn = 0; fn < 4; ++fn)
      for (int r = 0; r < 4; ++r) {
        int row = m0 + wr + fm * 16 + lhi * 4 + r;
        int col = n0 + wc + fn * 16 + l16;
        C[(size_t)row * N + col] = f2bf(acc[fm][fn][r]);
      }
}

// ---------------- build Qaug/Kaug/V from qkvb (bf16, vectorized) ----------------
__global__ __launch_bounds__(256) void augment_kernel(
    const ushort* __restrict__ qkvb,  // [B*T, 3072] bf16
    ushort* __restrict__ Qaug, ushort* __restrict__ Kaug, ushort* __restrict__ Vb) {
  int row = blockIdx.x;  // b*T + t
  int b = row >> 11;
  int t = row & 2047;
  int tid = threadIdx.x;
  const ushort* src = qkvb + (size_t)row * 3072;

  // base parts: thread handles 4 consecutive bf16 per slice (ushort4 in/out)
  {
    int d4 = tid * 4;             // 0..1020
    int h = d4 >> 6, d = d4 & 63;
    size_t obase = ((size_t)(b * H_ + h) * T_ + t);
    ushort4 q = *(const ushort4*)(src + d4);
    ushort4 k = *(const ushort4*)(src + 1024 + d4);
    ushort4 v = *(const ushort4*)(src + 2048 + d4);
    ushort4 qs;  // *0.125 = exponent-3: exact on bf16 (mantissa unchanged)
    qs.x = f2bf(b2f(q.x) * 0.125f); qs.y = f2bf(b2f(q.y) * 0.125f);
    qs.z = f2bf(b2f(q.z) * 0.125f); qs.w = f2bf(b2f(q.w) * 0.125f);
    *(ushort4*)(Qaug + obase * 128 + d) = qs;
    *(ushort4*)(Kaug + obase * 128 + d) = k;
    *(ushort4*)(Vb + obase * 64 + d) = v;
  }
  // trig parts: 512 slots = 16 h x 32 mm
  for (int i = 0; i < 2; ++i) {
    int idx = tid + i * 256;
    int h = idx >> 5, mm = idx & 31;
    int gdim = h * 64 + 2 * mm;
    float w = __expf(-9.2103403719761836f * (float)gdim * (1.0f / 1024.0f));
    float ang = w * (float)t;
    float si, co;
    __sincosf(ang, &si, &co);
    ushort2 qp = *(const ushort2*)(src + h * 64 + 2 * mm);
    float qs = b2f(qp.x), qc = b2f(qp.y);
    size_t obase = ((size_t)(b * H_ + h) * T_ + t);
    ushort2 qo, ko;
    qo.x = f2bf((qs * si + qc * co) * 0.125f);
    qo.y = f2bf((qc * si - qs * co) * 0.125f);
    ko.x = f2bf(co);
    ko.y = f2bf(si);
    *(ushort2*)(Qaug + obase * 128 + 64 + 2 * mm) = qo;
    *(ushort2*)(Kaug + obase * 128 + 64 + 2 * mm) = ko;
  }
}

// ---------------- transpose V: [BH, T, 64] -> [BH, 64, T] ----------------
__global__ __launch_bounds__(256) void transpose_v(const ushort* __restrict__ Vb,
                                                   ushort* __restrict__ Vt) {
  __shared__ ushort tile[64][72];
  int bh = blockIdx.y, t0 = blockIdx.x * 64;
  int tid = threadIdx.x;
  for (int i = 0; i < 2; ++i) {
    int e = tid + i * 256;
    int row = e >> 3, ch = e & 7;
    *(int4*)(&tile[row][ch * 8]) =
        *(const int4*)(Vb + ((size_t)bh * T_ + t0 + row) * 64 + ch * 8);
  }
  __syncthreads();
  for (int i = 0; i < 2; ++i) {
    int e = tid + i * 256;
    int d = e >> 3, ch = e & 7;
    union { int4 v; ushort u[8]; } pk;
    for (int u = 0; u < 8; ++u) pk.u[u] = tile[ch * 8 + u][d];
    *(int4*)(Vt + ((size_t)bh * 64 + d) * T_ + t0 + ch * 8) = pk.v;
  }
}

// row-within-32 for 32x32 MFMA C/D layout
__device__ __forceinline__ int rowf32(int reg, int hi) {
  return (reg & 3) + 8 * (reg >> 2) + 4 * hi;
}

// ---------------- denominator kernel: 32x32 MFMA, quadrant waves ----------------
__global__ __launch_bounds__(256, 4) void denom_kernel(
    const ushort* __restrict__ Qaug,  // [BH, T, 128]
    const ushort* __restrict__ Kaug,  // [BH, T, 128]
    float* __restrict__ invlb) {      // [BH, T]
  int flat = blockIdx.y * 32 + blockIdx.x;
  int wg = (flat & 7) * 128 + (flat >> 3);
  int bh = wg >> 5;
  int qt = 31 - (wg & 31);
  int tid = threadIdx.x;
  int wave = tid >> 6, lane = tid & 63;
  int l31 = lane & 31, hi = lane >> 5;
  int r = wave >> 1, d = wave & 1;

  __shared__ alignas(16) ushort Ks[2][8192];  // [key 0..63][128], chunk^(key&15)
  __shared__ float sums[64];

  const ushort* Kbase = Kaug + (size_t)bh * T_ * 128;

  auto stageK = [&](int kt, int buf) {
    for (int i = 0; i < 4; ++i) {
      int rg = i * 4 + wave;
      int key = rg * 4 + (lane >> 4);
      const ushort* g = Kbase + ((size_t)(kt * 64 + key)) * 128 + (((lane & 15) ^ (key & 15)) << 3);
      g2l16(g, &Ks[buf][rg * 512]);
    }
  };

  bf16x8 qf[8];
  {
    const ushort* Qg = Qaug + ((size_t)bh * T_ + qt * 64 + r * 32 + l31) * 128;
    for (int ks = 0; ks < 8; ++ks)
      qf[ks] = *(const bf16x8*)(Qg + ks * 16 + hi * 8);
  }
  int key = d * 32 + l31;

  stageK(0, 0);
  asm volatile("s_waitcnt vmcnt(0)" ::: "memory");
  __builtin_amdgcn_s_barrier();
  float plsum[16];
  for (int i = 0; i < 16; ++i) plsum[i] = 0.f;

  for (int kt = 0; kt <= qt; ++kt) {
    int buf = kt & 1;
    if (kt < qt) stageK(kt + 1, buf ^ 1);
    __builtin_amdgcn_sched_barrier(0);
    const ushort* Kb = Ks[buf];
    f32x16 s = {};
    for (int ks = 0; ks < 8; ++ks) {
      int slot = (ks * 2 + hi) ^ (key & 15);
      bf16x8 kf = *(const bf16x8*)(Kb + key * 128 + (slot << 3));
      s = __builtin_amdgcn_mfma_f32_32x32x16_bf16(qf[ks], kf, s, 0, 0, 0);
    }
    if (kt == qt) {
      for (int reg = 0; reg < 16; ++reg)
        if (d * 32 + l31 > r * 32 + rowf32(reg, hi)) s[reg] = -1e30f;
    }
    for (int reg = 0; reg < 16; ++reg) plsum[reg] += __expf(s[reg]);
    if (kt < qt) {
      asm volatile("s_waitcnt vmcnt(0)" ::: "memory");
      __builtin_amdgcn_s_barrier();
    }
  }
  for (int reg = 0; reg < 16; ++reg) {
    float v = plsum[reg];
    for (int dd = 1; dd < 32; dd <<= 1) v += __shfl_xor(v, dd);
    plsum[reg] = v;
  }
  if (d == 1 && l31 == 0)
    for (int reg = 0; reg < 16; ++reg)
      sums[r * 32 + rowf32(reg, hi)] = plsum[reg];
  __syncthreads();
  if (d == 0 && l31 == 0)
    for (int reg = 0; reg < 16; ++reg) {
      int row = r * 32 + rowf32(reg, hi);
      invlb[(size_t)bh * T_ + qt * 64 + row] = 1.f / (plsum[reg] + sums[row]);
    }
}

// ---------------- attention main: 32x32 MFMA, quadrant waves ----------------
__global__ __launch_bounds__(256) void attn2_kernel(
    const ushort* __restrict__ Qaug,  // [BH, T, 128]
    const ushort* __restrict__ Kaug,  // [BH, T, 128]
    const ushort* __restrict__ Vt,    // [BH, 64, T]
    const float* __restrict__ invlb,  // [BH, T]
    float* __restrict__ score,        // [BH, T, T]
    ushort* __restrict__ ctxb) {      // [B*T, 1024] bf16
  int flat = blockIdx.y * 32 + blockIdx.x;
  int wg = (flat & 7) * 128 + (flat >> 3);
  int bh = wg >> 5;
  int qt = 31 - (wg & 31);
  int tid = threadIdx.x;
  int wave = tid >> 6, lane = tid & 63;
  int l31 = lane & 31, hi = lane >> 5;
  int r = wave >> 1, d = wave & 1;

  __shared__ alignas(16) ushort Ks[2][8192];  // [key][128], chunk^(key&15)
  __shared__ alignas(16) ushort Vs[2][4096];  // [dim][64 keys], chunk^(dim&7)
  __shared__ alignas(16) ushort Ps[4096];     // [qrow][64 keys], chunk^(row&7)

  const ushort* Kbase = Kaug + (size_t)bh * T_ * 128;
  const ushort* Vbase = Vt + (size_t)bh * 64 * T_;

  auto stageK = [&](int kt, int buf) {
    for (int i = 0; i < 4; ++i) {
      int rg = i * 4 + wave;
      int key = rg * 4 + (lane >> 4);
      const ushort* g = Kbase + ((size_t)(kt * 64 + key)) * 128 + (((lane & 15) ^ (key & 15)) << 3);
      g2l16(g, &Ks[buf][rg * 512]);
    }
  };
  auto stageV = [&](int kt, int buf) {
    for (int i = 0; i < 2; ++i) {
      int rg = i * 4 + wave;
      int dim = rg * 8 + (lane >> 3);
      const ushort* g = Vbase + (size_t)dim * T_ + kt * 64 + (((lane & 7) ^ (dim & 7)) << 3);
      g2l16(g, &Vs[buf][rg * 512]);
    }
  };

  bf16x8 qf[8];
  {
    const ushort* Qg = Qaug + ((size_t)bh * T_ + qt * 64 + r * 32 + l31) * 128;
    for (int ks = 0; ks < 8; ++ks)
      qf[ks] = *(const bf16x8*)(Qg + ks * 16 + hi * 8);
  }
  int key = d * 32 + l31;
  float4 iv[4];
  for (int g = 0; g < 4; ++g)
    iv[g] = *(const float4*)(invlb + (size_t)bh * T_ + qt * 64 + r * 32 + hi * 4 + g * 8);

  stageK(0, 0);
  stageV(0, 0);
  asm volatile("s_waitcnt vmcnt(0)" ::: "memory");
  __builtin_amdgcn_s_barrier();
  f32x16 cacc[2] = {};
  float* srow = score + ((size_t)bh * T_ + (size_t)qt * 64) * T_;

  for (int kt = 0; kt <= qt; ++kt) {
    int buf = kt & 1;
    if (kt < qt) { stageK(kt + 1, buf ^ 1); stageV(kt + 1, buf ^ 1); }
    __builtin_amdgcn_sched_barrier(0);
    const ushort* Kb = Ks[buf];
    f32x16 s = {};
    for (int ks = 0; ks < 8; ++ks) {
      int slot = (ks * 2 + hi) ^ (key & 15);
      bf16x8 kf = *(const bf16x8*)(Kb + key * 128 + (slot << 3));
      s = __builtin_amdgcn_mfma_f32_32x32x16_bf16(qf[ks], kf, s, 0, 0, 0);
    }
    if (kt == qt) {
      for (int reg = 0; reg < 16; ++reg)
        if (d * 32 + l31 > r * 32 + rowf32(reg, hi)) s[reg] = -1e30f;
    }
    for (int reg = 0; reg < 16; ++reg) {
      int row_loc = r * 32 + rowf32(reg, hi);
      float p = __expf(s[reg]) * iv[reg >> 2][reg & 3];
      srow[(size_t)row_loc * T_ + kt * 64 + key] = p;
      Ps[row_loc * 64 + ((((key >> 3)) ^ (row_loc & 7)) << 3) + (key & 7)] = f2bf(p);
    }
    asm volatile("s_waitcnt lgkmcnt(0)" ::: "memory");
    __builtin_amdgcn_sched_barrier(0);
    const ushort* Vb2 = Vs[buf];
    int rowA = r * 32 + l31;
    for (int ks2 = 0; ks2 < 2; ++ks2) {
      int chunkA = d * 4 + ks2 * 2 + hi;
      bf16x8 pa = *(const bf16x8*)(Ps + rowA * 64 + ((chunkA ^ (rowA & 7)) << 3));
      for (int b2 = 0; b2 < 2; ++b2) {
        int dim = b2 * 32 + l31;
        bf16x8 vb = *(const bf16x8*)(Vb2 + dim * 64 + ((chunkA ^ (dim & 7)) << 3));
        cacc[b2] = __builtin_amdgcn_mfma_f32_32x32x16_bf16(pa, vb, cacc[b2], 0, 0, 0);
      }
    }
    if (kt < qt) {
      asm volatile("s_waitcnt vmcnt(16)" ::: "memory");
      __builtin_amdgcn_s_barrier();
    }
  }

  // zero-fill upper-triangle tiles of score
  {
    int row = tid >> 2, c16 = (tid & 3) * 16;
    f32x4 z = {0.f, 0.f, 0.f, 0.f};
    for (int kt = qt + 1; kt < 32; ++kt) {
      f32x4* dst = (f32x4*)(srow + (size_t)row * T_ + kt * 64 + c16);
      for (int u = 0; u < 4; ++u) dst[u] = z;
    }
  }

  // combine key-half partial ctx across wave pairs, write ctxb
  __builtin_amdgcn_s_barrier();
  float* xch = (float*)Ks;
  if (d == 1) {
    for (int b2 = 0; b2 < 2; ++b2)
      for (int reg = 0; reg < 16; ++reg)
        xch[(r * 32 + rowf32(reg, hi)) * 64 + b2 * 32 + l31] = cacc[b2][reg];
  }
  __syncthreads();
  if (d == 0) {
    int b = bh >> 4, h = bh & 15;
    for (int b2 = 0; b2 < 2; ++b2)
      for (int reg = 0; reg < 16; ++reg) {
        int row_loc = r * 32 + rowf32(reg, hi);
        float v = cacc[b2][reg] + xch[row_loc * 64 + b2 * 32 + l31];
        int t = qt * 64 + row_loc;
        ctxb[((size_t)(b * T_ + t)) * 1024 + h * 64 + b2 * 32 + l31] = f2bf(v);
      }
  }
}

extern "C" void kernel_launch(void* const* d_in, const int* in_sizes, int n_in,
                              void* d_out, int out_size, void* d_ws, size_t ws_size,
                              hipStream_t stream) {
  const float* x    = (const float*)d_in[0];
  const float* Wqkv = (const float*)d_in[2];
  const float* Wout = (const float*)d_in[3];
  const float* bout = (const float*)d_in[4];

  char* ws = (char*)d_ws;
  ushort* xb    = (ushort*)(ws + 0);           //  8 MB
  ushort* wqkvT = (ushort*)(ws + 8388608);     //  6 MB
  ushort* woutT = (ushort*)(ws + 14680064);    //  2 MB
  ushort* qkvb  = (ushort*)(ws + 16777216);    // 24 MB bf16 [B*T,3072]
  ushort* Qaug  = (ushort*)(ws + 50331648);    // 16 MB
  ushort* Kaug  = (ushort*)(ws + 67108864);    // 16 MB
  ushort* Vb    = (ushort*)(ws + 83886080);    //  8 MB
  ushort* Vt    = (ushort*)(ws + 92274688);    //  8 MB
  ushort* ctxb  = (ushort*)(ws + 100663296);   //  8 MB
  float*  invlb = (float*) (ws + 109051904);   // 256 KB

  float* out   = (float*)d_out;
  float* score = out + (size_t)4194304;  // B*T*D floats, then [B,H,T,T]

  cvt_kernel<<<4096, 256, 0, stream>>>(x, xb);
  dim3 tb(32, 8);
  transpose_cvt<<<dim3(3072 / 32, 1024 / 32), tb, 0, stream>>>(Wqkv, wqkvT, 1024, 3072);
  transpose_cvt<<<dim3(1024 / 32, 1024 / 32), tb, 0, stream>>>(Wout, woutT, 1024, 1024);
  gemm_bf16_ob<<<dim3(24, 32), 256, 0, stream>>>(xb, wqkvT, qkvb, 4096, 3072, 1024);
  augment_kernel<<<4096, 256, 0, stream>>>(qkvb, Qaug, Kaug, Vb);
  transpose_v<<<dim3(32, 32), 256, 0, stream>>>(Vb, Vt);
  denom_kernel<<<dim3(32, 32), 256, 0, stream>>>(Qaug, Kaug, invlb);
  attn2_kernel<<<dim3(32, 32), 256, 0, stream>>>(Qaug, Kaug, Vt, invlb, score, ctxb);
  gemm_bf16<<<dim3(8, 32), 256, 0, stream>>>(ctxb, woutT, out, bout, 4096, 1024, 1024);
}